// Round 3
// baseline (485.819 us; speedup 1.0000x reference)
//
#include <hip/hip_runtime.h>
#include <stdint.h>

#define B_ 2
#define E_ 8
#define N_ 1024
#define D_ 1024
#define H_ 4096

typedef float f32x4 __attribute__((ext_vector_type(4)));
typedef __bf16 bf16x8 __attribute__((ext_vector_type(8)));

__device__ __forceinline__ unsigned short f2bf(float f) {
  union { float f; uint32_t u; } v; v.f = f;
  uint32_t u = v.u;
  return (unsigned short)((u + 0x7FFFu + ((u >> 16) & 1u)) >> 16);  // RNE
}

__device__ __forceinline__ void gload_lds16(const unsigned short* g, unsigned short* l) {
  __builtin_amdgcn_global_load_lds(
      (__attribute__((address_space(1))) void*)g,
      (__attribute__((address_space(3))) void*)l,
      16, 0, 0);
}

// ---- elementwise fp32 -> bf16 convert (x) ----
__global__ void cvt_x_kernel(const float* __restrict__ in, unsigned short* __restrict__ out, int n4) {
  int idx = blockIdx.x * blockDim.x + threadIdx.x;
  int stride = gridDim.x * blockDim.x;
  const float4* in4 = (const float4*)in;
  ushort4* out4 = (ushort4*)out;
  for (int i = idx; i < n4; i += stride) {
    float4 f = in4[i];
    ushort4 o;
    o.x = f2bf(f.x); o.y = f2bf(f.y); o.z = f2bf(f.z); o.w = f2bf(f.w);
    out4[i] = o;
  }
}

// ---- tiled transpose + convert: in fp32 [R][C] per expert -> out bf16 [C][R] ----
__global__ void transpose_cvt_kernel(const float* __restrict__ in, unsigned short* __restrict__ out,
                                     int R, int C) {
  __shared__ float tile[32][33];
  const size_t eoff = (size_t)blockIdx.z * R * C;
  const float* src = in + eoff;
  unsigned short* dst = out + eoff;
  const int c0 = blockIdx.x * 32, r0 = blockIdx.y * 32;
  const int tx = threadIdx.x, ty = threadIdx.y;
#pragma unroll
  for (int i = 0; i < 4; ++i)
    tile[ty + 8 * i][tx] = src[(size_t)(r0 + ty + 8 * i) * C + c0 + tx];
  __syncthreads();
#pragma unroll
  for (int i = 0; i < 4; ++i)
    dst[(size_t)(c0 + ty + 8 * i) * R + r0 + tx] = f2bf(tile[tx][ty + 8 * i]);
}

// ============================================================================
// 256x256-tile, BK=64, 8-wave (2x4), 4-phase/K-tile bf16 MFMA GEMM.
// LDS: 8 DISTINCT named arrays (buf x {A,B} x khalf), 16 KiB each = 128 KiB.
// Distinct arrays + compile-time buffer selection (K-loop unrolled x2) let
// LLVM alias analysis prove phase ds_reads don't touch in-flight prefetch
// targets -> no conservative vmcnt(0); the only VMEM wait is the explicit
// counted vmcnt(4) at the tile boundary (T3+T4). T2 swizzle via pre-swizzled
// global source + swizzled ds_read slot. T5 setprio around MFMA clusters.
// Stage rotation per compute(t): P1->t+1.A.kh1, P2->t+1.B.kh1,
//                                P3->t+2.A.kh0, P4->t+2.B.kh0.
// ============================================================================
template <int K, int NCOLS, bool GELU>
__global__ __launch_bounds__(512, 2)
void gemm256_kernel(const unsigned short* __restrict__ A,
                    const unsigned short* __restrict__ Bt,
                    const float* __restrict__ bias,
                    unsigned short* __restrict__ OutBf,
                    float* __restrict__ OutF) {
  constexpr int MT = 2048 / 256;   // M tiles per expert (B_*N_ rows)
  constexpr int NTl = NCOLS / 256; // N tiles
  constexpr int NT = K / 64;       // K tiles (16 or 64 -> even)

  __shared__ __align__(16) unsigned short A0k0[8192], A0k1[8192], B0k0[8192], B0k1[8192];
  __shared__ __align__(16) unsigned short A1k0[8192], A1k1[8192], B1k0[8192], B1k1[8192];

  // T1: bijective XCD swizzle (gridDim.x % 8 == 0 for both GEMMs)
  const int nwg = gridDim.x;
  const int flat = blockIdx.x;
  const int swz = (flat & 7) * (nwg >> 3) + (flat >> 3);
  const int e = swz / (MT * NTl);
  const int rem = swz - e * (MT * NTl);
  const int nt = rem / MT;
  const int mt = rem - nt * MT;

  const int m0 = mt * 256;
  const int n0 = nt * 256;
  const int b = m0 >> 10;
  const int nl = m0 & 1023;
  const size_t arow0 = (size_t)((b * E_ + e) * N_ + nl);

  const unsigned short* Ab = A + arow0 * K;
  const unsigned short* Bb = Bt + ((size_t)e * NCOLS + n0) * K;

  const int tid = threadIdx.x;
  const int w = tid >> 6;
  const int lane = tid & 63;
  const int wr = w >> 2;        // 0..1  (M half: 128 rows)
  const int wc = w & 3;         // 0..3  (N quarter: 64 cols)
  const int fr = lane & 15;
  const int kg = lane >> 4;     // 0..3 (16B k-slot)
  const int sxor = kg ^ ((lane >> 1) & 3);  // swizzled read slot

  // staging source addressing (pre-swizzled so linear LDS dest ends up swizzled)
  const int scol = (((lane & 3) ^ ((lane >> 3) & 3)) << 3);  // k element offset
  const int srow0 = w * 32 + (lane >> 2);
  const int srow1 = w * 32 + 16 + (lane >> 2);
  const unsigned short* aS0 = Ab + (size_t)srow0 * K + scol;
  const unsigned short* aS1 = Ab + (size_t)srow1 * K + scol;
  const unsigned short* bS0 = Bb + (size_t)srow0 * K + scol;
  const unsigned short* bS1 = Bb + (size_t)srow1 * K + scol;

  // per-thread LDS read bases (element units within one 8192-elem array)
  const int aBase = (wr * 128 + fr) * 32 + sxor * 8;
  const int bBase = (wc * 64 + fr) * 32 + sxor * 8;

#define STAGE(ARR, S0_, S1_, t, kh) do {                           \
    const size_t ko_ = (size_t)(t) * 64 + (kh) * 32;               \
    gload_lds16(S0_ + ko_, &ARR[w * 1024]);                        \
    gload_lds16(S1_ + ko_, &ARR[w * 1024 + 512]);                  \
  } while (0)

  f32x4 acc[8][4];
#pragma unroll
  for (int i = 0; i < 8; ++i)
#pragma unroll
    for (int j = 0; j < 4; ++j)
      acc[i][j] = (f32x4){0.f, 0.f, 0.f, 0.f};

  // prologue: tile0 fully + tile1 khalf0; 2 half-tiles stay in flight
  STAGE(A0k0, aS0, aS1, 0, 0); STAGE(B0k0, bS0, bS1, 0, 0);
  STAGE(A0k1, aS0, aS1, 0, 1); STAGE(B0k1, bS0, bS1, 0, 1);
  STAGE(A1k0, aS0, aS1, 1, 0); STAGE(B1k0, bS0, bS1, 1, 0);
  asm volatile("s_waitcnt vmcnt(4)" ::: "memory");
  __builtin_amdgcn_s_barrier();

#define MFMA_CLUSTER(ROFF)                                                    \
    __builtin_amdgcn_s_setprio(1);                                            \
    _Pragma("unroll")                                                         \
    for (int mi = 0; mi < 4; ++mi)                                            \
      _Pragma("unroll")                                                       \
      for (int ni = 0; ni < 4; ++ni)                                          \
        acc[(ROFF) + mi][ni] =                                                \
            __builtin_amdgcn_mfma_f32_16x16x32_bf16(av[mi], bv[ni],           \
                                                    acc[(ROFF) + mi][ni], 0, 0, 0); \
    __builtin_amdgcn_s_setprio(0);

#define ITER(t, CA0, CA1, CB0, CB1, NA1, NB1) do {                            \
    bf16x8 av[4], bv[4];                                                      \
    /* ---- P1: kh=0, M rows 0-63 ---- */                                     \
    _Pragma("unroll")                                                         \
    for (int i = 0; i < 4; ++i) {                                             \
      av[i] = *(const bf16x8*)&CA0[aBase + i * 512];                          \
      bv[i] = *(const bf16x8*)&CB0[bBase + i * 512];                          \
    }                                                                         \
    if ((t) + 1 < NT) STAGE(NA1, aS0, aS1, (t) + 1, 1);                       \
    __builtin_amdgcn_s_barrier();                                             \
    asm volatile("s_waitcnt lgkmcnt(0)");                                     \
    MFMA_CLUSTER(0)                                                           \
    __builtin_amdgcn_s_barrier();                                             \
    /* ---- P2: kh=0, M rows 64-127 (reuse bv) ---- */                        \
    _Pragma("unroll")                                                         \
    for (int i = 0; i < 4; ++i)                                               \
      av[i] = *(const bf16x8*)&CA0[aBase + 2048 + i * 512];                   \
    if ((t) + 1 < NT) STAGE(NB1, bS0, bS1, (t) + 1, 1);                       \
    __builtin_amdgcn_s_barrier();                                             \
    asm volatile("s_waitcnt lgkmcnt(0)");                                     \
    MFMA_CLUSTER(4)                                                           \
    __builtin_amdgcn_s_barrier();                                             \
    /* ---- P3: kh=1, M rows 0-63 ---- */                                     \
    _Pragma("unroll")                                                         \
    for (int i = 0; i < 4; ++i) {                                             \
      av[i] = *(const bf16x8*)&CA1[aBase + i * 512];                          \
      bv[i] = *(const bf16x8*)&CB1[bBase + i * 512];                          \
    }                                                                         \
    if ((t) + 2 < NT) STAGE(CA0, aS0, aS1, (t) + 2, 0);                       \
    __builtin_amdgcn_s_barrier();                                             \
    asm volatile("s_waitcnt lgkmcnt(0)");                                     \
    MFMA_CLUSTER(0)                                                           \
    __builtin_amdgcn_s_barrier();                                             \
    /* ---- P4: kh=1, M rows 64-127 (reuse bv) ---- */                        \
    _Pragma("unroll")                                                         \
    for (int i = 0; i < 4; ++i)                                               \
      av[i] = *(const bf16x8*)&CA1[aBase + 2048 + i * 512];                   \
    if ((t) + 2 < NT) STAGE(CB0, bS0, bS1, (t) + 2, 0);                       \
    __builtin_amdgcn_s_barrier();                                             \
    asm volatile("s_waitcnt lgkmcnt(0)");                                     \
    MFMA_CLUSTER(4)                                                           \
    /* tile boundary: tile t+1 fully visible; 2 half-tiles stay in flight */  \
    asm volatile("s_waitcnt vmcnt(4)" ::: "memory");                          \
    __builtin_amdgcn_s_barrier();                                             \
  } while (0)

#pragma unroll 1
  for (int tt = 0; tt < NT; tt += 2) {
    ITER(tt,     A0k0, A0k1, B0k0, B0k1, A1k1, B1k1);
    ITER(tt + 1, A1k0, A1k1, B1k0, B1k1, A0k1, B0k1);
  }

#undef ITER
#undef MFMA_CLUSTER
#undef STAGE

  // epilogue: C/D layout col=lane&15, row=(lane>>4)*4+j  [round-1 verified]
  const int rb = kg * 4;
#pragma unroll
  for (int ni = 0; ni < 4; ++ni) {
    const int gc = n0 + wc * 64 + ni * 16 + fr;
    const float bval = bias[(size_t)e * NCOLS + gc];
#pragma unroll
    for (int MI = 0; MI < 8; ++MI) {
      const size_t orow = arow0 + (size_t)(wr * 128 + MI * 16 + rb);
#pragma unroll
      for (int j = 0; j < 4; ++j) {
        float v = acc[MI][ni][j] + bval;
        if constexpr (GELU) {
          float g = 0.5f * v * (1.0f + erff(v * 0.70710678118654752f));
          OutBf[(orow + j) * NCOLS + gc] = f2bf(g);
        } else {
          OutF[(orow + j) * NCOLS + gc] = v;
        }
      }
    }
  }
}

extern "C" void kernel_launch(void* const* d_in, const int* in_sizes, int n_in,
                              void* d_out, int out_size, void* d_ws, size_t ws_size,
                              hipStream_t stream) {
  const float* x  = (const float*)d_in[0];
  const float* w1 = (const float*)d_in[1];
  const float* b1 = (const float*)d_in[2];
  const float* w2 = (const float*)d_in[3];
  const float* b2 = (const float*)d_in[4];
  float* out = (float*)d_out;

  const size_t xN  = (size_t)B_ * E_ * N_ * D_;
  const size_t w1N = (size_t)E_ * D_ * H_;
  const size_t w2N = (size_t)E_ * H_ * D_;
  const size_t hN  = (size_t)B_ * E_ * N_ * H_;
  const size_t needed = (xN + w1N + w2N + hN) * 2;
  if (ws_size < needed) return;

  unsigned short* xb  = (unsigned short*)d_ws;
  unsigned short* w1t = xb + xN;   // [E][H][D] bf16
  unsigned short* w2t = w1t + w1N; // [E][D][H] bf16
  unsigned short* hb  = w2t + w2N; // [B][E][N][H] bf16

  cvt_x_kernel<<<2048, 256, 0, stream>>>(x, xb, (int)(xN / 4));
  dim3 tb(32, 8);
  transpose_cvt_kernel<<<dim3(H_ / 32, D_ / 32, E_), tb, 0, stream>>>(w1, w1t, D_, H_);
  transpose_cvt_kernel<<<dim3(D_ / 32, H_ / 32, E_), tb, 0, stream>>>(w2, w2t, H_, D_);

  // GEMM1: h = gelu(x @ w1 + b1); 8 * 16 * 8 = 1024 blocks
  gemm256_kernel<D_, H_, true><<<8 * (H_ / 256) * E_, 512, 0, stream>>>(xb, w1t, b1, hb, nullptr);
  // GEMM2: out = h @ w2 + b2; 8 * 4 * 8 = 256 blocks
  gemm256_kernel<H_, D_, false><<<8 * (D_ / 256) * E_, 512, 0, stream>>>(hb, w2t, b2, nullptr, out);
}

// Round 4
// 471.896 us; speedup vs baseline: 1.0295x; 1.0295x over previous
//
#include <hip/hip_runtime.h>
#include <stdint.h>

#define B_ 2
#define E_ 8
#define N_ 1024
#define D_ 1024
#define H_ 4096

typedef float f32x4 __attribute__((ext_vector_type(4)));
typedef __bf16 bf16x8 __attribute__((ext_vector_type(8)));
typedef __attribute__((address_space(3))) const unsigned short lds_cus;

__device__ __forceinline__ unsigned short f2bf(float f) {
  union { float f; uint32_t u; } v; v.f = f;
  uint32_t u = v.u;
  return (unsigned short)((u + 0x7FFFu + ((u >> 16) & 1u)) >> 16);  // RNE
}

__device__ __forceinline__ void gload_lds16(const unsigned short* g, unsigned short* l) {
  __builtin_amdgcn_global_load_lds(
      (__attribute__((address_space(1))) void*)g,
      (__attribute__((address_space(3))) void*)l,
      16, 0, 0);
}

// Inline-asm ds_read: register-only operands -> invisible to the waitcnt
// pass's VMEM->LDS RAW tracking -> no compiler-inserted vmcnt(0) drains.
// Synchronization is OUR lgkmcnt(0)+sched_barrier(0) and boundary vmcnt.
__device__ __forceinline__ bf16x8 lds_read_b128(lds_cus* p) {
  bf16x8 r;
  asm volatile("ds_read_b128 %0, %1" : "=v"(r) : "v"(p));
  return r;
}

// ---- elementwise fp32 -> bf16 convert (x) ----
__global__ void cvt_x_kernel(const float* __restrict__ in, unsigned short* __restrict__ out, int n4) {
  int idx = blockIdx.x * blockDim.x + threadIdx.x;
  int stride = gridDim.x * blockDim.x;
  const float4* in4 = (const float4*)in;
  ushort4* out4 = (ushort4*)out;
  for (int i = idx; i < n4; i += stride) {
    float4 f = in4[i];
    ushort4 o;
    o.x = f2bf(f.x); o.y = f2bf(f.y); o.z = f2bf(f.z); o.w = f2bf(f.w);
    out4[i] = o;
  }
}

// ---- tiled transpose + convert: in fp32 [R][C] per expert -> out bf16 [C][R] ----
__global__ void transpose_cvt_kernel(const float* __restrict__ in, unsigned short* __restrict__ out,
                                     int R, int C) {
  __shared__ float tile[32][33];
  const size_t eoff = (size_t)blockIdx.z * R * C;
  const float* src = in + eoff;
  unsigned short* dst = out + eoff;
  const int c0 = blockIdx.x * 32, r0 = blockIdx.y * 32;
  const int tx = threadIdx.x, ty = threadIdx.y;
#pragma unroll
  for (int i = 0; i < 4; ++i)
    tile[ty + 8 * i][tx] = src[(size_t)(r0 + ty + 8 * i) * C + c0 + tx];
  __syncthreads();
#pragma unroll
  for (int i = 0; i < 4; ++i)
    dst[(size_t)(c0 + ty + 8 * i) * R + r0 + tx] = f2bf(tile[tx][ty + 8 * i]);
}

// ============================================================================
// 256x256-tile, BK=64, 8-wave (2x4), 4-phase/K-tile bf16 MFMA GEMM.
// Same schedule as R3 but with asm ds_read_b128 (no compiler wait insertion),
// sched_barrier(0) after each lgkmcnt(0) (rule #18), and a tail-safe boundary
// wait (vmcnt(0) on the final two K-tiles; vmcnt(4) otherwise).
// Stage rotation per compute(t): P1->t+1.A.kh1, P2->t+1.B.kh1,
//                                P3->t+2.A.kh0, P4->t+2.B.kh0.
// ============================================================================
template <int K, int NCOLS, bool GELU>
__global__ __launch_bounds__(512, 2)
void gemm256_kernel(const unsigned short* __restrict__ A,
                    const unsigned short* __restrict__ Bt,
                    const float* __restrict__ bias,
                    unsigned short* __restrict__ OutBf,
                    float* __restrict__ OutF) {
  constexpr int MT = 2048 / 256;   // M tiles per expert (B_*N_ rows)
  constexpr int NTl = NCOLS / 256; // N tiles
  constexpr int NT = K / 64;       // K tiles (16 or 64 -> even, >= 4)

  __shared__ __align__(16) unsigned short A0k0[8192], A0k1[8192], B0k0[8192], B0k1[8192];
  __shared__ __align__(16) unsigned short A1k0[8192], A1k1[8192], B1k0[8192], B1k1[8192];

  // T1: bijective XCD swizzle (gridDim.x % 8 == 0 for both GEMMs)
  const int nwg = gridDim.x;
  const int flat = blockIdx.x;
  const int swz = (flat & 7) * (nwg >> 3) + (flat >> 3);
  const int e = swz / (MT * NTl);
  const int rem = swz - e * (MT * NTl);
  const int nt = rem / MT;
  const int mt = rem - nt * MT;

  const int m0 = mt * 256;
  const int n0 = nt * 256;
  const int b = m0 >> 10;
  const int nl = m0 & 1023;
  const size_t arow0 = (size_t)((b * E_ + e) * N_ + nl);

  const unsigned short* Ab = A + arow0 * K;
  const unsigned short* Bb = Bt + ((size_t)e * NCOLS + n0) * K;

  const int tid = threadIdx.x;
  const int w = tid >> 6;
  const int lane = tid & 63;
  const int wr = w >> 2;        // 0..1  (M half: 128 rows)
  const int wc = w & 3;         // 0..3  (N quarter: 64 cols)
  const int fr = lane & 15;
  const int kg = lane >> 4;     // 0..3 (16B k-slot)
  const int sxor = kg ^ ((lane >> 1) & 3);  // swizzled read slot

  // staging source addressing (pre-swizzled so linear LDS dest ends up swizzled)
  const int scol = (((lane & 3) ^ ((lane >> 3) & 3)) << 3);  // k element offset
  const int srow0 = w * 32 + (lane >> 2);
  const int srow1 = w * 32 + 16 + (lane >> 2);
  const unsigned short* aS0 = Ab + (size_t)srow0 * K + scol;
  const unsigned short* aS1 = Ab + (size_t)srow1 * K + scol;
  const unsigned short* bS0 = Bb + (size_t)srow0 * K + scol;
  const unsigned short* bS1 = Bb + (size_t)srow1 * K + scol;

  // per-thread LDS read bases (element units within one 8192-elem array)
  const int aBase = (wr * 128 + fr) * 32 + sxor * 8;
  const int bBase = (wc * 64 + fr) * 32 + sxor * 8;

#define STAGE(ARR, S0_, S1_, t, kh) do {                           \
    const size_t ko_ = (size_t)(t) * 64 + (kh) * 32;               \
    gload_lds16(S0_ + ko_, &ARR[w * 1024]);                        \
    gload_lds16(S1_ + ko_, &ARR[w * 1024 + 512]);                  \
  } while (0)

  f32x4 acc[8][4];
#pragma unroll
  for (int i = 0; i < 8; ++i)
#pragma unroll
    for (int j = 0; j < 4; ++j)
      acc[i][j] = (f32x4){0.f, 0.f, 0.f, 0.f};

  // prologue: tile0 fully + tile1 khalf0; 2 half-tiles (4 instrs) stay in flight
  STAGE(A0k0, aS0, aS1, 0, 0); STAGE(B0k0, bS0, bS1, 0, 0);
  STAGE(A0k1, aS0, aS1, 0, 1); STAGE(B0k1, bS0, bS1, 0, 1);
  STAGE(A1k0, aS0, aS1, 1, 0); STAGE(B1k0, bS0, bS1, 1, 0);
  asm volatile("s_waitcnt vmcnt(4)" ::: "memory");
  __builtin_amdgcn_s_barrier();

#define WAIT_LGKM() do {                                                      \
    asm volatile("s_waitcnt lgkmcnt(0)");                                     \
    __builtin_amdgcn_sched_barrier(0);                                        \
  } while (0)

#define MFMA_CLUSTER(ROFF)                                                    \
    __builtin_amdgcn_s_setprio(1);                                            \
    _Pragma("unroll")                                                         \
    for (int mi = 0; mi < 4; ++mi)                                            \
      _Pragma("unroll")                                                       \
      for (int ni = 0; ni < 4; ++ni)                                          \
        acc[(ROFF) + mi][ni] =                                                \
            __builtin_amdgcn_mfma_f32_16x16x32_bf16(av[mi], bv[ni],           \
                                                    acc[(ROFF) + mi][ni], 0, 0, 0); \
    __builtin_amdgcn_s_setprio(0);

#define ITER(t, CA0, CA1, CB0, CB1, NA1, NB1) do {                            \
    bf16x8 av[4], bv[4];                                                      \
    /* ---- P1: kh=0, M rows 0-63 ---- */                                     \
    _Pragma("unroll")                                                         \
    for (int i = 0; i < 4; ++i) {                                             \
      av[i] = lds_read_b128((lds_cus*)&CA0[aBase + i * 512]);                 \
      bv[i] = lds_read_b128((lds_cus*)&CB0[bBase + i * 512]);                 \
    }                                                                         \
    if ((t) + 1 < NT) STAGE(NA1, aS0, aS1, (t) + 1, 1);                       \
    __builtin_amdgcn_s_barrier();                                             \
    WAIT_LGKM();                                                              \
    MFMA_CLUSTER(0)                                                           \
    __builtin_amdgcn_s_barrier();                                             \
    /* ---- P2: kh=0, M rows 64-127 (reuse bv) ---- */                        \
    _Pragma("unroll")                                                         \
    for (int i = 0; i < 4; ++i)                                               \
      av[i] = lds_read_b128((lds_cus*)&CA0[aBase + 2048 + i * 512]);          \
    if ((t) + 1 < NT) STAGE(NB1, bS0, bS1, (t) + 1, 1);                       \
    __builtin_amdgcn_s_barrier();                                             \
    WAIT_LGKM();                                                              \
    MFMA_CLUSTER(4)                                                           \
    __builtin_amdgcn_s_barrier();                                             \
    /* ---- P3: kh=1, M rows 0-63 ---- */                                     \
    _Pragma("unroll")                                                         \
    for (int i = 0; i < 4; ++i) {                                             \
      av[i] = lds_read_b128((lds_cus*)&CA1[aBase + i * 512]);                 \
      bv[i] = lds_read_b128((lds_cus*)&CB1[bBase + i * 512]);                 \
    }                                                                         \
    if ((t) + 2 < NT) STAGE(CA0, aS0, aS1, (t) + 2, 0);                       \
    __builtin_amdgcn_s_barrier();                                             \
    WAIT_LGKM();                                                              \
    MFMA_CLUSTER(0)                                                           \
    __builtin_amdgcn_s_barrier();                                             \
    /* ---- P4: kh=1, M rows 64-127 (reuse bv) ---- */                        \
    _Pragma("unroll")                                                         \
    for (int i = 0; i < 4; ++i)                                               \
      av[i] = lds_read_b128((lds_cus*)&CA1[aBase + 2048 + i * 512]);          \
    if ((t) + 2 < NT) STAGE(CB0, bS0, bS1, (t) + 2, 0);                       \
    __builtin_amdgcn_s_barrier();                                             \
    WAIT_LGKM();                                                              \
    MFMA_CLUSTER(4)                                                           \
    /* tile boundary: tile t+1 fully visible. Steady state: 2 half-tiles */   \
    /* (4 instrs) in flight -> vmcnt(4). Tail (no t+2 stages): vmcnt(0) */    \
    /* so the final tile's kh1 stages are actually drained (R2/R3 race). */   \
    if ((t) + 2 < NT) { asm volatile("s_waitcnt vmcnt(4)" ::: "memory"); }    \
    else              { asm volatile("s_waitcnt vmcnt(0)" ::: "memory"); }    \
    __builtin_amdgcn_s_barrier();                                             \
  } while (0)

#pragma unroll 1
  for (int tt = 0; tt < NT; tt += 2) {
    ITER(tt,     A0k0, A0k1, B0k0, B0k1, A1k1, B1k1);
    ITER(tt + 1, A1k0, A1k1, B1k0, B1k1, A0k1, B0k1);
  }

#undef ITER
#undef MFMA_CLUSTER
#undef WAIT_LGKM
#undef STAGE

  // epilogue: C/D layout col=lane&15, row=(lane>>4)*4+j  [round-1 verified]
  const int rb = kg * 4;
#pragma unroll
  for (int ni = 0; ni < 4; ++ni) {
    const int gc = n0 + wc * 64 + ni * 16 + fr;
    const float bval = bias[(size_t)e * NCOLS + gc];
#pragma unroll
    for (int MI = 0; MI < 8; ++MI) {
      const size_t orow = arow0 + (size_t)(wr * 128 + MI * 16 + rb);
#pragma unroll
      for (int j = 0; j < 4; ++j) {
        float v = acc[MI][ni][j] + bval;
        if constexpr (GELU) {
          float g = 0.5f * v * (1.0f + erff(v * 0.70710678118654752f));
          OutBf[(orow + j) * NCOLS + gc] = f2bf(g);
        } else {
          OutF[(orow + j) * NCOLS + gc] = v;
        }
      }
    }
  }
}

extern "C" void kernel_launch(void* const* d_in, const int* in_sizes, int n_in,
                              void* d_out, int out_size, void* d_ws, size_t ws_size,
                              hipStream_t stream) {
  const float* x  = (const float*)d_in[0];
  const float* w1 = (const float*)d_in[1];
  const float* b1 = (const float*)d_in[2];
  const float* w2 = (const float*)d_in[3];
  const float* b2 = (const float*)d_in[4];
  float* out = (float*)d_out;

  const size_t xN  = (size_t)B_ * E_ * N_ * D_;
  const size_t w1N = (size_t)E_ * D_ * H_;
  const size_t w2N = (size_t)E_ * H_ * D_;
  const size_t hN  = (size_t)B_ * E_ * N_ * H_;
  const size_t needed = (xN + w1N + w2N + hN) * 2;
  if (ws_size < needed) return;

  unsigned short* xb  = (unsigned short*)d_ws;
  unsigned short* w1t = xb + xN;   // [E][H][D] bf16
  unsigned short* w2t = w1t + w1N; // [E][D][H] bf16
  unsigned short* hb  = w2t + w2N; // [B][E][N][H] bf16

  cvt_x_kernel<<<2048, 256, 0, stream>>>(x, xb, (int)(xN / 4));
  dim3 tb(32, 8);
  transpose_cvt_kernel<<<dim3(H_ / 32, D_ / 32, E_), tb, 0, stream>>>(w1, w1t, D_, H_);
  transpose_cvt_kernel<<<dim3(D_ / 32, H_ / 32, E_), tb, 0, stream>>>(w2, w2t, H_, D_);

  // GEMM1: h = gelu(x @ w1 + b1); 8 * 16 * 8 = 1024 blocks
  gemm256_kernel<D_, H_, true><<<8 * (H_ / 256) * E_, 512, 0, stream>>>(xb, w1t, b1, hb, nullptr);
  // GEMM2: out = h @ w2 + b2; 8 * 4 * 8 = 256 blocks
  gemm256_kernel<H_, D_, false><<<8 * (D_ / 256) * E_, 512, 0, stream>>>(hb, w2t, b2, nullptr, out);
}